// Round 1
// baseline (405.471 us; speedup 1.0000x reference)
//
#include <hip/hip_runtime.h>

#define BLOCK 256   // 4 waves per block; each wave handles 16 rows (1 row per quad)

__device__ __forceinline__ float rfl(float x) {
  // force wave-uniform value into an SGPR
  return __uint_as_float(__builtin_amdgcn_readfirstlane(__float_as_uint(x)));
}

// ---- DPP cross-lane xor helpers (VALU pipe). quad_perm ops stay inside a quad. ----
template<int CTRL>
__device__ __forceinline__ float dppmov(float x) {
  return __int_as_float(__builtin_amdgcn_update_dpp(
      0, __float_as_int(x), CTRL, 0xf, 0xf, true));
}
__device__ __forceinline__ float dx1(float x) { return dppmov<0xB1>(x); }  // quad_perm [1,0,3,2] == xor1
__device__ __forceinline__ float dx2(float x) { return dppmov<0x4E>(x); }  // quad_perm [2,3,0,1] == xor2
__device__ __forceinline__ float dx4(float x) {
  return dppmov<0x1B>(dppmov<0x141>(x));  // xor7 then xor3 == xor4
}
__device__ __forceinline__ float dx8(float x) { return dppmov<0x128>(x); } // row_ror:8 == xor8
__device__ __forceinline__ float sx16(float x) { return __shfl_xor(x, 16, 64); }
__device__ __forceinline__ float sx32(float x) { return __shfl_xor(x, 32, 64); }

__device__ __forceinline__ float wave_allsum(float x) {
  x += dx1(x); x += dx2(x); x += dx4(x); x += dx8(x);
  x += sx16(x); x += sx32(x);
  return x;
}

// Mapping: amp index s (8 bits). s bits 0..5 -> register index k of a[64]
// (bit i of k == qubit i). s bit6 -> lane bit0, s bit7 -> lane bit1.
// Quad g = (lane>>2) owns row (wave*16 + g). All 4 lanes of a quad hold the
// same row's f[] after the 2-level quad reduce; each lane then evolves its
// own (q6,q7) sector of 64 amplitudes.

__global__ __launch_bounds__(BLOCK, 4) void qsco_kernel(
    const float* __restrict__ E,
    const float* __restrict__ ln_gamma,
    const float* __restrict__ ln_beta,
    const float* __restrict__ Wpre,   // [8,512]
    const float* __restrict__ bpre,   // [8]
    const float* __restrict__ theta,  // [8]
    const float* __restrict__ Wpost,  // [1,8]
    const float* __restrict__ bpost,  // [1]
    float* __restrict__ out,
    int nrows)
{
  __shared__ float Wg[8][512];   // gamma-premultiplied W, 16 KB

  const int tid  = threadIdx.x;
  const int lane = tid & 63;

  // ---- stage Wg = gamma .* Wpre into LDS (cooperative, once per block) ----
#pragma unroll
  for (int t = 0; t < 4; ++t) {
    const int e4 = (t * BLOCK + tid) << 2;   // float index in [0, 4096)
    const int j = e4 >> 9, k = e4 & 511;
    const float4 w = *(const float4*)(Wpre + j * 512 + k);
    const float4 g = *(const float4*)(ln_gamma + k);
    float4 r;
    r.x = w.x * g.x; r.y = w.y * g.y; r.z = w.z * g.z; r.w = w.w * g.w;
    *(float4*)(&Wg[j][k]) = r;
  }
  __syncthreads();

  // ---- per-wave uniform constants: G_j = sum(gamma.*W_j), K_j = beta.W_j + bpre_j ----
  const int k0 = lane << 3;  // 8 floats per lane covers 512
  const float4 gamA = *(const float4*)(ln_gamma + k0);
  const float4 gamB = *(const float4*)(ln_gamma + k0 + 4);
  const float4 betA = *(const float4*)(ln_beta + k0);
  const float4 betB = *(const float4*)(ln_beta + k0 + 4);
  float G[8], K[8];
#pragma unroll
  for (int j = 0; j < 8; ++j) {
    const float4 wA = *(const float4*)(Wpre + j * 512 + k0);
    const float4 wB = *(const float4*)(Wpre + j * 512 + k0 + 4);
    const float gs = wA.x*gamA.x + wA.y*gamA.y + wA.z*gamA.z + wA.w*gamA.w
                   + wB.x*gamB.x + wB.y*gamB.y + wB.z*gamB.z + wB.w*gamB.w;
    const float ks = wA.x*betA.x + wA.y*betA.y + wA.z*betA.z + wA.w*betA.w
                   + wB.x*betB.x + wB.y*betB.y + wB.z*betB.z + wB.w*betB.w;
    G[j] = rfl(wave_allsum(gs));
    K[j] = rfl(wave_allsum(ks) + bpre[j]);
  }

  // theta trig (wave-uniform -> SGPR)
  float cT[8], sT[8];
#pragma unroll
  for (int q = 0; q < 8; ++q) {
    const float h = 0.5f * theta[q];
    cT[q] = rfl(__cosf(h));
    sT[q] = rfl(__sinf(h));
  }
  // per-lane signed sin for the two lane-bit qubits (q6 = lane bit0, q7 = lane bit1)
  const float ss6 = (lane & 1) ? sT[6] : -sT[6];
  const float ss7 = (lane & 2) ? sT[7] : -sT[7];

  // measurement weights
  float al[8];
#pragma unroll
  for (int q = 0; q < 8; ++q) al[q] = rfl(Wpost[q]);
  const float lsign = ((lane & 1) ? -al[6] : al[6]) + ((lane & 2) ? -al[7] : al[7]);
  const float bp = rfl(bpost[0]);

  // ---- row assignment ----
  const int wave = blockIdx.x * (BLOCK / 64) + (tid >> 6);
  const int row  = wave * 16 + (lane >> 2);
  const int sub  = lane & 3;                 // k-chunk slot within quad
  const float* Erow = E + (size_t)(row < nrows ? row : 0) * 512 + (sub << 2);

  // ---- dot phase: 10 accumulators over this lane's 128 elements ----
  // lane's k-set: {sub*4 + 16*i + 0..3 | i=0..31}; a quad covers 64 contiguous
  // bytes per iteration (streaming-friendly); Wg reads are quad-broadcast
  // (16 lanes same address) -> conflict-free.
  float f[10];
#pragma unroll
  for (int t = 0; t < 10; ++t) f[t] = 0.f;
#pragma unroll 4
  for (int i = 0; i < 32; ++i) {
    const float4 ev = *(const float4*)(Erow + (i << 4));
    const int kk = (sub << 2) + (i << 4);
    f[0] += (ev.x + ev.y) + (ev.z + ev.w);
    f[1] += ev.x*ev.x + ev.y*ev.y + ev.z*ev.z + ev.w*ev.w;
#pragma unroll
    for (int j = 0; j < 8; ++j) {
      const float4 w = *(const float4*)(&Wg[j][kk]);
      f[2 + j] += ev.x*w.x + ev.y*w.y + ev.z*w.z + ev.w*w.w;
    }
  }
  // quad reduce (2 DPP levels) -> all 4 lanes hold the row's full sums
#pragma unroll
  for (int t = 0; t < 10; ++t) f[t] += dx1(f[t]);
#pragma unroll
  for (int t = 0; t < 10; ++t) f[t] += dx2(f[t]);

  const float mu   = f[0] * (1.0f / 512.0f);
  const float var  = f[1] * (1.0f / 512.0f) - mu * mu;
  const float rstd = rsqrtf(var + 1e-5f);

  float ca[8], sa[8];
#pragma unroll
  for (int j = 0; j < 8; ++j) {
    const float ang = rstd * (f[2 + j] - mu * G[j]) + K[j];
    const float h = 0.5f * ang;
    ca[j] = __cosf(h);
    sa[j] = __sinf(h);
  }

  // ---- initial product state: 64 amps per lane ----
  float a[64];
  a[0] = ((lane & 1) ? sa[6] : ca[6]) * ((lane & 2) ? sa[7] : ca[7]);
#pragma unroll
  for (int b = 0; b < 6; ++b) {
    const int m = 1 << b;
#pragma unroll
    for (int k = 0; k < 32; ++k) {
      if (k < m) {
        a[k + m] = a[k] * sa[b];
        a[k]     = a[k] * ca[b];
      }
    }
  }

  // ---- circuit: DEPTH=2 of [CNOT ring 0->1..7->0, then RY(all)] ----
#pragma unroll
  for (int d = 0; d < 2; ++d) {
    // CNOT(0,1): control bit0, target bit1 — register rename
#pragma unroll
    for (int k = 0; k < 64; ++k) if ((k & 1) && !(k & 2)) {
      const float t_ = a[k]; a[k] = a[k ^ 2]; a[k ^ 2] = t_;
    }
    // CNOT(1,2)
#pragma unroll
    for (int k = 0; k < 64; ++k) if ((k & 2) && !(k & 4)) {
      const float t_ = a[k]; a[k] = a[k ^ 4]; a[k ^ 4] = t_;
    }
    // CNOT(2,3)
#pragma unroll
    for (int k = 0; k < 64; ++k) if ((k & 4) && !(k & 8)) {
      const float t_ = a[k]; a[k] = a[k ^ 8]; a[k ^ 8] = t_;
    }
    // CNOT(3,4)
#pragma unroll
    for (int k = 0; k < 64; ++k) if ((k & 8) && !(k & 16)) {
      const float t_ = a[k]; a[k] = a[k ^ 16]; a[k ^ 16] = t_;
    }
    // CNOT(4,5)
#pragma unroll
    for (int k = 0; k < 64; ++k) if ((k & 16) && !(k & 32)) {
      const float t_ = a[k]; a[k] = a[k ^ 32]; a[k ^ 32] = t_;
    }
    // CNOT(5,6): control reg bit5, target lane bit0 — swap across lanes for k>=32
#pragma unroll
    for (int k = 32; k < 64; ++k) a[k] = dx1(a[k]);
    // CNOT(6,7): control lane bit0, target lane bit1
    {
      const bool c = (lane & 1) != 0;
#pragma unroll
      for (int k = 0; k < 64; ++k) {
        const float t_ = dx2(a[k]);
        a[k] = c ? t_ : a[k];
      }
    }
    // CNOT(7,0): control lane bit1, target reg bit0 — conditional pair swap
    {
      const bool c = (lane & 2) != 0;
#pragma unroll
      for (int m = 0; m < 32; ++m) {
        const float x = a[2 * m], y = a[2 * m + 1];
        a[2 * m]     = c ? y : x;
        a[2 * m + 1] = c ? x : y;
      }
    }
    // RY on register qubits 0..5 (cos/sin in SGPRs, pure FMA)
#pragma unroll
    for (int i = 0; i < 6; ++i) {
      const int m = 1 << i;
      const float cc = cT[i], sn = sT[i];
#pragma unroll
      for (int k = 0; k < 64; ++k) if (!(k & m)) {
        const float x = a[k], y = a[k | m];
        a[k]     = cc * x - sn * y;
        a[k | m] = sn * x + cc * y;
      }
    }
    // RY(6): butterfly on lane bit0
#pragma unroll
    for (int k = 0; k < 64; ++k) {
      const float p = dx1(a[k]);
      a[k] = cT[6] * a[k] + ss6 * p;
    }
    // RY(7): butterfly on lane bit1
#pragma unroll
    for (int k = 0; k < 64; ++k) {
      const float p = dx2(a[k]);
      a[k] = cT[7] * a[k] + ss7 * p;
    }
  }

  // ---- measurement: v = sum_s |A_s|^2 * D_s, D_s = sum_i al_i*(1-2 s_i) ----
  // probabilities in-place
#pragma unroll
  for (int k = 0; k < 64; ++k) a[k] = a[k] * a[k];
  // binary tree over reg bits: zr[b] = Z of qubit b (reg part), a[0] -> total
  float zr[6];
#pragma unroll
  for (int b = 0; b < 6; ++b) {
    const int n = 32 >> b;
    float zb = 0.f;
#pragma unroll
    for (int m = 0; m < 32; ++m) {
      if (m < n) {
        const float p = a[2 * m], q = a[2 * m + 1];
        zb   += (p - q);
        a[m]  = p + q;
      }
    }
    zr[b] = zb;
  }
  float vL = lsign * a[0];   // lane-bit qubits' contribution: (+-al6 +-al7) * P(lane sector)
#pragma unroll
  for (int i = 0; i < 6; ++i) vL += al[i] * zr[i];
  // sum the 4 (q6,q7) sectors of the quad
  vL += dx1(vL);
  vL += dx2(vL);
  if (sub == 0 && row < nrows) out[row] = vL + bp;
}

extern "C" void kernel_launch(void* const* d_in, const int* in_sizes, int n_in,
                              void* d_out, int out_size, void* d_ws, size_t ws_size,
                              hipStream_t stream) {
  const float* E        = (const float*)d_in[0];
  const float* ln_gamma = (const float*)d_in[1];
  const float* ln_beta  = (const float*)d_in[2];
  const float* Wpre     = (const float*)d_in[3];
  const float* bpre     = (const float*)d_in[4];
  const float* theta    = (const float*)d_in[5];
  const float* Wpost    = (const float*)d_in[6];
  const float* bpost    = (const float*)d_in[7];
  float* out = (float*)d_out;

  const int nrows = in_sizes[0] / 512;
  const int rows_per_block = (BLOCK / 64) * 16;   // 4 waves * 16 rows
  const int grid = (nrows + rows_per_block - 1) / rows_per_block;
  qsco_kernel<<<grid, BLOCK, 0, stream>>>(E, ln_gamma, ln_beta, Wpre, bpre,
                                          theta, Wpost, bpost, out, nrows);
}

// Round 2
// 392.440 us; speedup vs baseline: 1.0332x; 1.0332x over previous
//
#include <hip/hip_runtime.h>

#define BLOCK 256   // 4 waves per block; each wave handles 16 rows (1 row per quad)

typedef float v2f __attribute__((ext_vector_type(2)));

__device__ __forceinline__ float rfl(float x) {
  return __uint_as_float(__builtin_amdgcn_readfirstlane(__float_as_uint(x)));
}
__device__ __forceinline__ v2f mk2(float x, float y) { v2f r; r.x = x; r.y = y; return r; }
__device__ __forceinline__ v2f sp2(float x) { v2f r; r.x = x; r.y = x; return r; }
__device__ __forceinline__ v2f pkfma(v2f a, v2f b, v2f c) {
  return __builtin_elementwise_fma(a, b, c);
}
__device__ __forceinline__ v2f swap2(v2f v) { return __builtin_shufflevector(v, v, 1, 0); }

// ---- DPP cross-lane helpers (VALU pipe, quad-local unless noted) ----
template<int CTRL>
__device__ __forceinline__ float dppmov(float x) {
  return __int_as_float(__builtin_amdgcn_update_dpp(
      0, __float_as_int(x), CTRL, 0xf, 0xf, true));
}
__device__ __forceinline__ float dx1(float x) { return dppmov<0xB1>(x); }  // quad_perm [1,0,3,2] == xor1
__device__ __forceinline__ float dx2(float x) { return dppmov<0x4E>(x); }  // quad_perm [2,3,0,1] == xor2
__device__ __forceinline__ float dswap13(float x) { return dppmov<0x6C>(x); } // quad_perm [0,3,2,1]
__device__ __forceinline__ float dx4(float x) {
  return dppmov<0x1B>(dppmov<0x141>(x));
}
__device__ __forceinline__ float dx8(float x) { return dppmov<0x128>(x); } // row_ror:8 == xor8
__device__ __forceinline__ float sx16(float x) { return __shfl_xor(x, 16, 64); }
__device__ __forceinline__ float sx32(float x) { return __shfl_xor(x, 32, 64); }

__device__ __forceinline__ float wave_allsum(float x) {
  x += dx1(x); x += dx2(x); x += dx4(x); x += dx8(x);
  x += sx16(x); x += sx32(x);
  return x;
}

// Mapping: amp index s (8 bits). s bits 0..4 -> index k of a2[32] (bit i == qubit i).
// s bit5 -> float2 component (.x = q5=0, .y = q5=1).
// s bit6 -> lane bit0, s bit7 -> lane bit1. Quad g=(lane>>2) owns row wave*16+g.

__global__ __launch_bounds__(BLOCK, 4) void qsco_kernel(
    const float* __restrict__ E,
    const float* __restrict__ ln_gamma,
    const float* __restrict__ ln_beta,
    const float* __restrict__ Wpre,   // [8,512]
    const float* __restrict__ bpre,   // [8]
    const float* __restrict__ theta,  // [8]
    const float* __restrict__ Wpost,  // [1,8]
    const float* __restrict__ bpost,  // [1]
    float* __restrict__ out,
    int nrows)
{
  __shared__ float Wg[8][512];   // gamma-premultiplied W, 16 KB

  const int tid  = threadIdx.x;
  const int lane = tid & 63;

  // ---- stage Wg = gamma .* Wpre into LDS ----
#pragma unroll
  for (int t = 0; t < 4; ++t) {
    const int e4 = (t * BLOCK + tid) << 2;
    const int j = e4 >> 9, k = e4 & 511;
    const float4 w = *(const float4*)(Wpre + j * 512 + k);
    const float4 g = *(const float4*)(ln_gamma + k);
    float4 r;
    r.x = w.x * g.x; r.y = w.y * g.y; r.z = w.z * g.z; r.w = w.w * g.w;
    *(float4*)(&Wg[j][k]) = r;
  }
  __syncthreads();

  // ---- per-wave uniform constants ----
  const int k0 = lane << 3;
  const float4 gamA = *(const float4*)(ln_gamma + k0);
  const float4 gamB = *(const float4*)(ln_gamma + k0 + 4);
  const float4 betA = *(const float4*)(ln_beta + k0);
  const float4 betB = *(const float4*)(ln_beta + k0 + 4);
  float G[8], K[8];
#pragma unroll
  for (int j = 0; j < 8; ++j) {
    const float4 wA = *(const float4*)(Wpre + j * 512 + k0);
    const float4 wB = *(const float4*)(Wpre + j * 512 + k0 + 4);
    const float gs = wA.x*gamA.x + wA.y*gamA.y + wA.z*gamA.z + wA.w*gamA.w
                   + wB.x*gamB.x + wB.y*gamB.y + wB.z*gamB.z + wB.w*gamB.w;
    const float ks = wA.x*betA.x + wA.y*betA.y + wA.z*betA.z + wA.w*betA.w
                   + wB.x*betB.x + wB.y*betB.y + wB.z*betB.z + wB.w*betB.w;
    G[j] = rfl(wave_allsum(gs));
    K[j] = rfl(wave_allsum(ks) + bpre[j]);
  }

  // theta trig (wave-uniform -> SGPR)
  float cT[8], sT[8];
#pragma unroll
  for (int q = 0; q < 8; ++q) {
    const float h = 0.5f * theta[q];
    cT[q] = rfl(__cosf(h));
    sT[q] = rfl(__sinf(h));
  }
  const float ss6 = (lane & 1) ? sT[6] : -sT[6];
  const float ss7 = (lane & 2) ? sT[7] : -sT[7];

  float al[8];
#pragma unroll
  for (int q = 0; q < 8; ++q) al[q] = rfl(Wpost[q]);
  const float lsign = ((lane & 1) ? -al[6] : al[6]) + ((lane & 2) ? -al[7] : al[7]);
  const float bp = rfl(bpost[0]);

  // ---- row assignment ----
  const int wave = blockIdx.x * (BLOCK / 64) + (tid >> 6);
  const int row  = wave * 16 + (lane >> 2);
  const int sub  = lane & 3;
  const float* Erow = E + (size_t)(row < nrows ? row : 0) * 512 + (sub << 2);

  // ---- dot phase: 10 packed accumulators over this lane's 128 elements ----
  v2f f2[10];
#pragma unroll
  for (int t = 0; t < 10; ++t) f2[t] = sp2(0.f);
#pragma unroll 4
  for (int i = 0; i < 32; ++i) {
    const float4 ev = *(const float4*)(Erow + (i << 4));
    const v2f eA = mk2(ev.x, ev.y), eB = mk2(ev.z, ev.w);
    const int kk = (sub << 2) + (i << 4);
    f2[0] += eA + eB;
    f2[1] = pkfma(eA, eA, pkfma(eB, eB, f2[1]));
#pragma unroll
    for (int j = 0; j < 8; ++j) {
      const float4 w = *(const float4*)(&Wg[j][kk]);
      f2[2 + j] = pkfma(eA, mk2(w.x, w.y), pkfma(eB, mk2(w.z, w.w), f2[2 + j]));
    }
  }
  // horizontal + quad reduce (2 DPP levels)
  float f[10];
#pragma unroll
  for (int t = 0; t < 10; ++t) f[t] = f2[t].x + f2[t].y;
#pragma unroll
  for (int t = 0; t < 10; ++t) f[t] += dx1(f[t]);
#pragma unroll
  for (int t = 0; t < 10; ++t) f[t] += dx2(f[t]);

  const float mu   = f[0] * (1.0f / 512.0f);
  const float var  = f[1] * (1.0f / 512.0f) - mu * mu;
  const float rstd = rsqrtf(var + 1e-5f);

  float ca[8], sa[8];
#pragma unroll
  for (int j = 0; j < 8; ++j) {
    const float ang = rstd * (f[2 + j] - mu * G[j]) + K[j];
    const float h = 0.5f * ang;
    ca[j] = __cosf(h);
    sa[j] = __sinf(h);
  }

  // ---- initial product state: 32 packed amps per lane ----
  v2f a2[32];
  {
    const float base = ((lane & 1) ? sa[6] : ca[6]) * ((lane & 2) ? sa[7] : ca[7]);
    a2[0] = mk2(ca[5] * base, sa[5] * base);
#pragma unroll
    for (int b = 0; b < 5; ++b) {
      const int m = 1 << b;
      const v2f cb = sp2(ca[b]), sb = sp2(sa[b]);
#pragma unroll
      for (int k = 0; k < 16; ++k) {
        if (k < m) {
          a2[k + m] = a2[k] * sb;
          a2[k]     = a2[k] * cb;
        }
      }
    }
  }

  // packed theta constants
  const v2f cT2_0 = sp2(cT[0]), sT2_0 = sp2(sT[0]), nT2_0 = sp2(-sT[0]);
  const v2f cT2_1 = sp2(cT[1]), sT2_1 = sp2(sT[1]), nT2_1 = sp2(-sT[1]);
  const v2f cT2_2 = sp2(cT[2]), sT2_2 = sp2(sT[2]), nT2_2 = sp2(-sT[2]);
  const v2f cT2_3 = sp2(cT[3]), sT2_3 = sp2(sT[3]), nT2_3 = sp2(-sT[3]);
  const v2f cT2_4 = sp2(cT[4]), sT2_4 = sp2(sT[4]), nT2_4 = sp2(-sT[4]);
  const v2f cT2_5 = sp2(cT[5]);
  const v2f sm5   = mk2(-sT[5], sT[5]);   // RY(5) cross-component signs
  const v2f cT2_6 = sp2(cT[6]), ss6v = sp2(ss6);
  const v2f cT2_7 = sp2(cT[7]), ss7v = sp2(ss7);

#define RY_REG(CC, SS, NN, M) { \
    _Pragma("unroll") \
    for (int k = 0; k < 32; ++k) if (!(k & (M))) { \
      const v2f x = a2[k], y = a2[k | (M)]; \
      a2[k]       = pkfma(NN, y, CC * x); \
      a2[k | (M)] = pkfma(SS, x, CC * y); \
    } }

  // ---- circuit: DEPTH=2 of [CNOT ring, RY all] ----
#pragma unroll
  for (int d = 0; d < 2; ++d) {
    // CNOT(0,1): bit0 controls bit1 — rename
#pragma unroll
    for (int k = 0; k < 32; ++k) if ((k & 1) && !(k & 2)) {
      const v2f t_ = a2[k]; a2[k] = a2[k ^ 2]; a2[k ^ 2] = t_;
    }
    // CNOT(1,2)
#pragma unroll
    for (int k = 0; k < 32; ++k) if ((k & 2) && !(k & 4)) {
      const v2f t_ = a2[k]; a2[k] = a2[k ^ 4]; a2[k ^ 4] = t_;
    }
    // CNOT(2,3)
#pragma unroll
    for (int k = 0; k < 32; ++k) if ((k & 4) && !(k & 8)) {
      const v2f t_ = a2[k]; a2[k] = a2[k ^ 8]; a2[k ^ 8] = t_;
    }
    // CNOT(3,4)
#pragma unroll
    for (int k = 0; k < 32; ++k) if ((k & 8) && !(k & 16)) {
      const v2f t_ = a2[k]; a2[k] = a2[k ^ 16]; a2[k ^ 16] = t_;
    }
    // CNOT(4,5): bit4 controls component — swap halves
#pragma unroll
    for (int k = 16; k < 32; ++k) a2[k] = swap2(a2[k]);
    // CNOT(5,6): component .y controls lane bit0 — unconditional xor1 on .y
#pragma unroll
    for (int k = 0; k < 32; ++k) a2[k].y = dx1(a2[k].y);
    // CNOT(6,7): lane bit0 controls lane bit1 — full quad permutation [0,3,2,1]
#pragma unroll
    for (int k = 0; k < 32; ++k) {
      a2[k].x = dswap13(a2[k].x);
      a2[k].y = dswap13(a2[k].y);
    }
    // CNOT(7,0): lane bit1 controls reg bit0 — conditional pair swap
    {
      const bool c = (lane & 2) != 0;
#pragma unroll
      for (int m = 0; m < 16; ++m) {
        const v2f x = a2[2 * m], y = a2[2 * m + 1];
        a2[2 * m].x     = c ? y.x : x.x;
        a2[2 * m].y     = c ? y.y : x.y;
        a2[2 * m + 1].x = c ? x.x : y.x;
        a2[2 * m + 1].y = c ? x.y : y.y;
      }
    }
    // RY on register qubits 0..4 (packed butterflies)
    RY_REG(cT2_0, sT2_0, nT2_0, 1)
    RY_REG(cT2_1, sT2_1, nT2_1, 2)
    RY_REG(cT2_2, sT2_2, nT2_2, 4)
    RY_REG(cT2_3, sT2_3, nT2_3, 8)
    RY_REG(cT2_4, sT2_4, nT2_4, 16)
    // RY(5): cross-component rotation
#pragma unroll
    for (int k = 0; k < 32; ++k) {
      const v2f t_ = swap2(a2[k]);
      a2[k] = pkfma(sm5, t_, cT2_5 * a2[k]);
    }
    // RY(6): butterfly on lane bit0
#pragma unroll
    for (int k = 0; k < 32; ++k) {
      const v2f p = mk2(dx1(a2[k].x), dx1(a2[k].y));
      a2[k] = pkfma(ss6v, p, cT2_6 * a2[k]);
    }
    // RY(7): butterfly on lane bit1
#pragma unroll
    for (int k = 0; k < 32; ++k) {
      const v2f p = mk2(dx2(a2[k].x), dx2(a2[k].y));
      a2[k] = pkfma(ss7v, p, cT2_7 * a2[k]);
    }
  }
#undef RY_REG

  // ---- measurement ----
#pragma unroll
  for (int k = 0; k < 32; ++k) a2[k] = a2[k] * a2[k];
  v2f zr2[5];
#pragma unroll
  for (int b = 0; b < 5; ++b) {
    const int n = 16 >> b;
    v2f zb = sp2(0.f);
#pragma unroll
    for (int m = 0; m < 16; ++m) {
      if (m < n) {
        const v2f p = a2[2 * m], q = a2[2 * m + 1];
        zb   += (p - q);
        a2[m] = p + q;
      }
    }
    zr2[b] = zb;
  }
  const float z5  = a2[0].x - a2[0].y;
  const float tot = a2[0].x + a2[0].y;
  float vL = lsign * tot + al[5] * z5;
#pragma unroll
  for (int b = 0; b < 5; ++b) vL += al[b] * (zr2[b].x + zr2[b].y);
  vL += dx1(vL);
  vL += dx2(vL);
  if (sub == 0 && row < nrows) out[row] = vL + bp;
}

extern "C" void kernel_launch(void* const* d_in, const int* in_sizes, int n_in,
                              void* d_out, int out_size, void* d_ws, size_t ws_size,
                              hipStream_t stream) {
  const float* E        = (const float*)d_in[0];
  const float* ln_gamma = (const float*)d_in[1];
  const float* ln_beta  = (const float*)d_in[2];
  const float* Wpre     = (const float*)d_in[3];
  const float* bpre     = (const float*)d_in[4];
  const float* theta    = (const float*)d_in[5];
  const float* Wpost    = (const float*)d_in[6];
  const float* bpost    = (const float*)d_in[7];
  float* out = (float*)d_out;

  const int nrows = in_sizes[0] / 512;
  const int rows_per_block = (BLOCK / 64) * 16;
  const int grid = (nrows + rows_per_block - 1) / rows_per_block;
  qsco_kernel<<<grid, BLOCK, 0, stream>>>(E, ln_gamma, ln_beta, Wpre, bpre,
                                          theta, Wpost, bpost, out, nrows);
}